// Round 9
// baseline (183.137 us; speedup 1.0000x reference)
//
#include <hip/hip_runtime.h>
#include <math.h>

// Problem constants (B=2,H=12,Q=2048,K=2048,D=128,NPOS=512)
#define DD    128
#define NPOS  512
#define KK    2048
#define RPB   16        // rows per block = MFMA M dimension
#define BLK   1024      // 16 waves: one wave per row in phase 2

typedef __attribute__((ext_vector_type(8))) short short8_t;  // 8 bf16 (4 VGPRs)
typedef __attribute__((ext_vector_type(4))) float f32x4;

union BfPack {
    unsigned u[4];
    short8_t v;
};

__device__ __forceinline__ float sigmoidf_fast(float x) {
    // v_exp_f32 + v_rcp_f32, no IEEE-div sequence
    return __builtin_amdgcn_rcpf(1.0f + __expf(-x));
}

// truncate two fp32 to bf16, packed into one dword (hi<<16 | lo)
__device__ __forceinline__ unsigned pack_bf16(float lo, float hi) {
    return (__float_as_uint(hi) & 0xffff0000u) | (__float_as_uint(lo) >> 16);
}

__global__ __launch_bounds__(BLK, 8)
void cope_kernel(const float* __restrict__ query,     // [R, D]
                 const float* __restrict__ attn,      // [R, K]
                 const float* __restrict__ pos_emb,   // [D, NPOS]
                 const int*   __restrict__ npos_max_p,
                 float* __restrict__ out)              // [R, K]
{
    const int t    = threadIdx.x;
    const int wv   = t >> 6;       // wave id 0..15
    const int lane = t & 63;

    __shared__ float s_tab[RPB][NPOS + 1];   // +1 sentinel col for ifl+1 read

    const size_t row_base = (size_t)blockIdx.x * RPB;

    // ---------------- Phase 1: table GEMM via bf16 MFMA ----------------
    // Output [16 rows x 512 cols]; wave wv owns cols [wv*32, wv*32+32).
    {
        const int m  = lane & 15;
        const int g  = lane >> 4;
        const int n0 = wv * 32 + m;            // nt=0 column, nt=1 is +16

        f32x4 acc0 = {0.f, 0.f, 0.f, 0.f};
        f32x4 acc1 = {0.f, 0.f, 0.f, 0.f};

        #pragma unroll
        for (int kk = 0; kk < 4; ++kk) {
            const int k0 = kk * 32 + g * 8;

            // A fragment: 8 contiguous k of query row m
            const float* qp = query + (row_base + m) * DD + k0;
            f32x4 a0 = *reinterpret_cast<const f32x4*>(qp);
            f32x4 a1 = *reinterpret_cast<const f32x4*>(qp + 4);
            BfPack af;
            af.u[0] = pack_bf16(a0.x, a0.y);
            af.u[1] = pack_bf16(a0.z, a0.w);
            af.u[2] = pack_bf16(a1.x, a1.y);
            af.u[3] = pack_bf16(a1.z, a1.w);

            // B fragments: pos_emb[k][n], k strided by NPOS
            const float* bp = pos_emb + (size_t)k0 * NPOS + n0;
            float b0[8], b1[8];
            #pragma unroll
            for (int j = 0; j < 8; ++j) {
                b0[j] = bp[(size_t)j * NPOS];
                b1[j] = bp[(size_t)j * NPOS + 16];
            }
            BfPack bf0, bf1;
            #pragma unroll
            for (int j = 0; j < 4; ++j) {
                bf0.u[j] = pack_bf16(b0[2 * j], b0[2 * j + 1]);
                bf1.u[j] = pack_bf16(b1[2 * j], b1[2 * j + 1]);
            }

            acc0 = __builtin_amdgcn_mfma_f32_16x16x32_bf16(af.v, bf0.v, acc0, 0, 0, 0);
            acc1 = __builtin_amdgcn_mfma_f32_16x16x32_bf16(af.v, bf1.v, acc1, 0, 0, 0);
        }

        #pragma unroll
        for (int r = 0; r < 4; ++r) {
            s_tab[g * 4 + r][n0]      = acc0[r];
            s_tab[g * 4 + r][n0 + 16] = acc1[r];
        }
        if (t < RPB) s_tab[t][NPOS] = 0.0f;   // sentinel (w=0 there)
    }
    __syncthreads();

    // ---------------- Phase 2: reverse-streamed scan + gather ----------
    // Chunks processed 7..0; suffix carry in a scalar `running`.
    // 2-deep explicit load prefetch; store each chunk immediately.
    const size_t row = row_base + wv;
    const float* arow = attn + row * (size_t)KK;
    float*       orow = out  + row * (size_t)KK;
    const float* tab  = s_tab[wv];

    const float clampv = (float)(*npos_max_p - 1);
    const int   la4    = lane * 4;

    f32x4 gv_a = *reinterpret_cast<const f32x4*>(arow + 7 * 256 + la4);
    f32x4 gv_b = *reinterpret_cast<const f32x4*>(arow + 6 * 256 + la4);

    float running = 0.0f;

    #pragma unroll
    for (int c = 7; c >= 0; --c) {
        f32x4 gv = gv_a;
        gv_a = gv_b;
        if (c >= 2)
            gv_b = *reinterpret_cast<const f32x4*>(arow + (c - 2) * 256 + la4);

        // sigmoid + in-lane inclusive suffix (4 elems)
        float p3 = sigmoidf_fast(gv.w);
        float p2 = sigmoidf_fast(gv.z) + p3;
        float p1 = sigmoidf_fast(gv.y) + p2;
        float p0 = sigmoidf_fast(gv.x) + p1;
        const float lct = p0;

        // wave-level inclusive suffix scan of lane totals
        float v = lct;
        #pragma unroll
        for (int off = 1; off < 64; off <<= 1) {
            float u = __shfl_down(v, off);
            if (lane + off < 64) v += u;
        }

        const float base = running + (v - lct);

        // pos -> gather -> lerp -> NT store (immediately)
        f32x4 res;
        float pel[4] = {p0, p1, p2, p3};
        #pragma unroll
        for (int j = 0; j < 4; ++j) {
            float pos = fminf(pel[j] + base, clampv);
            int   ifl = (int)pos;          // pos >= 0, trunc == floor
            float wgt = pos - (float)ifl;
            float lf  = tab[ifl];
            float lc  = tab[ifl + 1];      // sentinel makes ifl=511 safe
            res[j] = fmaf(wgt, lc - lf, lf);
        }
        __builtin_nontemporal_store(res,
            reinterpret_cast<f32x4*>(orow + c * 256 + la4));

        running += __shfl(v, 0);           // add chunk total (lane0 of scan)
    }
}

extern "C" void kernel_launch(void* const* d_in, const int* in_sizes, int n_in,
                              void* d_out, int out_size, void* d_ws, size_t ws_size,
                              hipStream_t stream) {
    const float* query   = (const float*)d_in[0];
    const float* attn    = (const float*)d_in[1];
    const float* pos_emb = (const float*)d_in[2];
    const int*   nposp   = (const int*)d_in[3];
    float*       outp    = (float*)d_out;

    const int rows   = in_sizes[1] / KK;   // B*H*Q = 49152
    const int blocks = rows / RPB;         // 3072

    cope_kernel<<<blocks, BLK, 0, stream>>>(query, attn, pos_emb, nposp, outp);
}